// Round 1
// baseline (20501.648 us; speedup 1.0000x reference)
//
#include <hip/hip_runtime.h>

#define S 25
#define SP 29            // 25 + 2*2 halo
#define PLANE 625        // 25*25
#define VOL 390625       // 25^4

// Stage one zero-padded 29x29 (d2,d3) plane into LDS.
__device__ __forceinline__ void stage_plane(const float* __restrict__ src,
                                            float* plane, int tid, int nthr, bool inr)
{
    if (!inr) return;  // plane unused this iteration (compute is skipped)
    for (int i = tid; i < SP * SP; i += nthr) {
        int r = i / SP, c = i - r * SP;
        int d2e = r - 2, d3e = c - 2;
        float v = 0.f;
        if (d2e >= 0 && d2e < S && d3e >= 0 && d3e < S) v = src[d2e * S + d3e];
        plane[i] = v;
    }
}

// Layer 1: x [2,1,25^4] -> h [2,16,25^4]
// c<8:  relu(conv(x,w0)+b0) + relu(conv(x,w0_swap)+b0)   w0: (8,1,3,3,5,5)
// c>=8: relu(conv(x,w1)+b1) + relu(conv(x,w1_swap)+b1)   w1: (8,1,5,5,5,5)
__global__ __launch_bounds__(640) void layer1_kernel(
    const float* __restrict__ x,
    const float* __restrict__ w0, const float* __restrict__ b0,
    const float* __restrict__ w1, const float* __restrict__ b1,
    float* __restrict__ h)
{
    __shared__ float plane[SP * SP];
    const int blk = blockIdx.x;
    const int b = blk / PLANE;
    const int d01 = blk - b * PLANE;
    const int d0 = d01 / S, d1 = d01 - d0 * S;
    const int tid = threadIdx.x;
    const int td2 = tid / S, td3 = tid - td2 * S;
    const bool active = tid < PLANE;

    float accP[16], accS[16];
    #pragma unroll
    for (int c = 0; c < 16; ++c) { accP[c] = 0.f; accS[c] = 0.f; }

    const float* xb = x + (size_t)b * VOL;

    #pragma unroll 1
    for (int k01 = 0; k01 < 25; ++k01) {
        const int kd0 = k01 / 5, kd1 = k01 - kd0 * 5;
        const int e0 = d0 + kd0 - 2, e1 = d1 + kd1 - 2;
        const bool inr = (e0 >= 0 && e0 < S && e1 >= 0 && e1 < S);
        __syncthreads();
        stage_plane(xb + (e0 * S + e1) * PLANE, plane, tid, 640, inr);
        __syncthreads();
        if (!inr || !active) continue;

        float v[25];
        #pragma unroll
        for (int a = 0; a < 5; ++a)
            #pragma unroll
            for (int c2 = 0; c2 < 5; ++c2)
                v[a * 5 + c2] = plane[(td2 + a) * SP + td3 + c2];

        // w1 plain: w1[c][0][kd0][kd1][kd2][kd3]
        #pragma unroll
        for (int c = 0; c < 8; ++c) {
            const float* wp = w1 + ((c * 5 + kd0) * 5 + kd1) * 25;
            float s = 0.f;
            #pragma unroll
            for (int t = 0; t < 25; ++t) s += v[t] * wp[t];
            accP[8 + c] += s;
        }
        // w1 swapped: w1[c][0][kd2][kd3][kd0][kd1]
        #pragma unroll
        for (int c = 0; c < 8; ++c) {
            const float* wp = w1 + c * 625 + kd0 * 5 + kd1;
            float s = 0.f;
            #pragma unroll
            for (int t = 0; t < 25; ++t) s += v[t] * wp[t * 25];
            accS[8 + c] += s;
        }
        // w0 plain (3,3,5,5): only when kd0,kd1 in [1,3]
        if (kd0 >= 1 && kd0 <= 3 && kd1 >= 1 && kd1 <= 3) {
            #pragma unroll
            for (int c = 0; c < 8; ++c) {
                const float* wp = w0 + ((c * 3 + (kd0 - 1)) * 3 + (kd1 - 1)) * 25;
                float s = 0.f;
                #pragma unroll
                for (int t = 0; t < 25; ++t) s += v[t] * wp[t];
                accP[c] += s;
            }
        }
        // w0 swapped (5,5,3,3): taps (kd2,kd3) in 3x3, offsets +-1
        #pragma unroll
        for (int c = 0; c < 8; ++c) {
            const float* wp = w0 + c * 225 + kd0 * 5 + kd1;
            float s = 0.f;
            #pragma unroll
            for (int t2 = 0; t2 < 3; ++t2)
                #pragma unroll
                for (int t3 = 0; t3 < 3; ++t3)
                    s += v[(t2 + 1) * 5 + (t3 + 1)] * wp[(t2 * 3 + t3) * 25];
            accS[c] += s;
        }
    }
    if (!active) return;
    const int p = d01 * PLANE + tid;  // tid = td2*25+td3
    float* hb = h + (size_t)b * 16 * VOL;
    #pragma unroll
    for (int c = 0; c < 16; ++c) {
        float bias = (c < 8) ? b0[c] : b1[c - 8];
        hb[(size_t)c * VOL + p] = fmaxf(accP[c] + bias, 0.f) + fmaxf(accS[c] + bias, 0.f);
    }
}

// 16->16 conv, k=5^4, relu+bias. SWAP selects pair-swapped weight indexing.
template <int SWAP>
__global__ __launch_bounds__(640) void conv16x16_kernel(
    const float* __restrict__ in, const float* __restrict__ w,
    const float* __restrict__ bias, float* __restrict__ out)
{
    __shared__ float plane[SP * SP];
    const int blk = blockIdx.x;
    const int b = blk / PLANE;
    const int d01 = blk - b * PLANE;
    const int d0 = d01 / S, d1 = d01 - d0 * S;
    const int tid = threadIdx.x;
    const int td2 = tid / S, td3 = tid - td2 * S;
    const bool active = tid < PLANE;

    float acc[16];
    #pragma unroll
    for (int i = 0; i < 16; ++i) acc[i] = 0.f;

    #pragma unroll 1
    for (int ci = 0; ci < 16; ++ci) {
        const float* inb = in + ((size_t)b * 16 + ci) * VOL;
        #pragma unroll 1
        for (int k01 = 0; k01 < 25; ++k01) {
            const int kd0 = k01 / 5, kd1 = k01 - kd0 * 5;
            const int e0 = d0 + kd0 - 2, e1 = d1 + kd1 - 2;
            const bool inr = (e0 >= 0 && e0 < S && e1 >= 0 && e1 < S);
            __syncthreads();
            stage_plane(inb + (e0 * S + e1) * PLANE, plane, tid, 640, inr);
            __syncthreads();
            if (!inr || !active) continue;

            float v[25];
            #pragma unroll
            for (int a = 0; a < 5; ++a)
                #pragma unroll
                for (int c2 = 0; c2 < 5; ++c2)
                    v[a * 5 + c2] = plane[(td2 + a) * SP + td3 + c2];

            #pragma unroll
            for (int co = 0; co < 16; ++co) {
                const float* wp = w + ((co * 16 + ci) * 625) + (SWAP ? (kd0 * 5 + kd1) : k01 * 25);
                float s = 0.f;
                #pragma unroll
                for (int t = 0; t < 25; ++t)
                    s += v[t] * (SWAP ? wp[t * 25] : wp[t]);
                acc[co] += s;
            }
        }
    }
    if (!active) return;
    const int p = d01 * PLANE + tid;
    float* ob = out + (size_t)b * 16 * VOL;
    #pragma unroll
    for (int co = 0; co < 16; ++co)
        ob[(size_t)co * VOL + p] = fmaxf(acc[co] + bias[co], 0.f);
}

// 16->1 conv, k=5^4, relu+bias, optional accumulate into out.
// 128 threads; thread (gq,c) computes 5 outputs d2=gq*5..gq*5+4 at d3=c
// via a 9x5 register window (45 LDS reads / 125 FMA per (ci,k01)).
template <int SWAP, int ADD>
__global__ __launch_bounds__(128) void conv16x1_kernel(
    const float* __restrict__ g, const float* __restrict__ w,
    const float* __restrict__ bias, float* __restrict__ out)
{
    __shared__ float plane[SP * SP];
    const int blk = blockIdx.x;
    const int b = blk / PLANE;
    const int d01 = blk - b * PLANE;
    const int d0 = d01 / S, d1 = d01 - d0 * S;
    const int tid = threadIdx.x;
    const bool active = tid < 125;
    const int gq = tid / 25, c = tid - gq * 25;

    float acc[5];
    #pragma unroll
    for (int r = 0; r < 5; ++r) acc[r] = 0.f;

    #pragma unroll 1
    for (int ci = 0; ci < 16; ++ci) {
        const float* gb = g + ((size_t)b * 16 + ci) * VOL;
        #pragma unroll 1
        for (int k01 = 0; k01 < 25; ++k01) {
            const int kd0 = k01 / 5, kd1 = k01 - kd0 * 5;
            const int e0 = d0 + kd0 - 2, e1 = d1 + kd1 - 2;
            const bool inr = (e0 >= 0 && e0 < S && e1 >= 0 && e1 < S);
            __syncthreads();
            stage_plane(gb + (e0 * S + e1) * PLANE, plane, tid, 128, inr);
            __syncthreads();
            if (!inr || !active) continue;

            float v[45];
            #pragma unroll
            for (int rr = 0; rr < 9; ++rr)
                #pragma unroll
                for (int cc = 0; cc < 5; ++cc)
                    v[rr * 5 + cc] = plane[(gq * 5 + rr) * SP + c + cc];

            const float* wp = w + ci * 625 + (SWAP ? (kd0 * 5 + kd1) : k01 * 25);
            #pragma unroll
            for (int r = 0; r < 5; ++r)
                #pragma unroll
                for (int kd2 = 0; kd2 < 5; ++kd2)
                    #pragma unroll
                    for (int kd3 = 0; kd3 < 5; ++kd3)
                        acc[r] += v[(r + kd2) * 5 + kd3] *
                                  (SWAP ? wp[(kd2 * 5 + kd3) * 25] : wp[kd2 * 5 + kd3]);
        }
    }
    if (!active) return;
    const float bv = bias[0];
    #pragma unroll
    for (int r = 0; r < 5; ++r) {
        const int p = d01 * PLANE + (gq * 5 + r) * S + c;
        const float val = fmaxf(acc[r] + bv, 0.f);
        if (ADD) out[(size_t)b * VOL + p] += val;
        else     out[(size_t)b * VOL + p] = val;
    }
}

extern "C" void kernel_launch(void* const* d_in, const int* in_sizes, int n_in,
                              void* d_out, int out_size, void* d_ws, size_t ws_size,
                              hipStream_t stream) {
    const float* x   = (const float*)d_in[0];
    const float* w0  = (const float*)d_in[1];
    const float* b0  = (const float*)d_in[2];
    const float* w1  = (const float*)d_in[3];
    const float* b1  = (const float*)d_in[4];
    const float* w2a = (const float*)d_in[5];
    const float* b2a = (const float*)d_in[6];
    const float* w2b = (const float*)d_in[7];
    const float* b2b = (const float*)d_in[8];
    float* out = (float*)d_out;

    const size_t hvol = (size_t)2 * 16 * VOL;   // 12.5M floats = 50 MB
    if (ws_size < 2 * hvol * sizeof(float)) return;  // need h + g = 100 MB
    float* h = (float*)d_ws;
    float* g = h + hvol;

    const int nblk = 2 * PLANE;  // 1250

    layer1_kernel<<<nblk, 640, 0, stream>>>(x, w0, b0, w1, b1, h);

    // path A (plain weights): h -> g -> out (store)
    conv16x16_kernel<0><<<nblk, 640, 0, stream>>>(h, w2a, b2a, g);
    conv16x1_kernel<0, 0><<<nblk, 128, 0, stream>>>(g, w2b, b2b, out);

    // path B (pair-swapped weights): h -> g -> out (accumulate)
    conv16x16_kernel<1><<<nblk, 640, 0, stream>>>(h, w2a, b2a, g);
    conv16x1_kernel<1, 1><<<nblk, 128, 0, stream>>>(g, w2b, b2b, out);
}

// Round 2
// 18750.757 us; speedup vs baseline: 1.0934x; 1.0934x over previous
//
#include <hip/hip_runtime.h>

#define S 25
#define SP 29            // 25 + 2*2 halo
#define PLANE 625        // 25*25
#define VOL 390625       // 25^4

// Stage one zero-padded 29x29 (d2,d3) plane into LDS (nthr threads).
__device__ __forceinline__ void stage_plane_n(const float* __restrict__ src,
                                              float* plane, int tid, int nthr)
{
    for (int i = tid; i < SP * SP; i += nthr) {
        int r = i / SP, c = i - r * SP;
        int d2e = r - 2, d3e = c - 2;
        float v = 0.f;
        if (d2e >= 0 && d2e < S && d3e >= 0 && d3e < S) v = src[d2e * S + d3e];
        plane[i] = v;
    }
}

// Layer 1: x [2,1,25^4] -> h [2,16,25^4]
// c<8:  relu(conv(x,w0)+b0) + relu(conv(x,w0_swap)+b0)   w0: (8,1,3,3,5,5)
// c>=8: relu(conv(x,w1)+b1) + relu(conv(x,w1_swap)+b1)   w1: (8,1,5,5,5,5)
__global__ __launch_bounds__(640) void layer1_kernel(
    const float* __restrict__ x,
    const float* __restrict__ w0, const float* __restrict__ b0,
    const float* __restrict__ w1, const float* __restrict__ b1,
    float* __restrict__ h)
{
    __shared__ float plane[SP * SP];
    const int blk = blockIdx.x;
    const int b = blk / PLANE;
    const int d01 = blk - b * PLANE;
    const int d0 = d01 / S, d1 = d01 - d0 * S;
    const int tid = threadIdx.x;
    const int td2 = tid / S, td3 = tid - td2 * S;
    const bool active = tid < PLANE;

    float accP[16], accS[16];
    #pragma unroll
    for (int c = 0; c < 16; ++c) { accP[c] = 0.f; accS[c] = 0.f; }

    const float* xb = x + (size_t)b * VOL;

    #pragma unroll 1
    for (int k01 = 0; k01 < 25; ++k01) {
        const int kd0 = k01 / 5, kd1 = k01 - kd0 * 5;
        const int e0 = d0 + kd0 - 2, e1 = d1 + kd1 - 2;
        const bool inr = (e0 >= 0 && e0 < S && e1 >= 0 && e1 < S);
        __syncthreads();
        if (inr) stage_plane_n(xb + (e0 * S + e1) * PLANE, plane, tid, 640);
        __syncthreads();
        if (!inr || !active) continue;

        float v[25];
        #pragma unroll
        for (int a = 0; a < 5; ++a)
            #pragma unroll
            for (int c2 = 0; c2 < 5; ++c2)
                v[a * 5 + c2] = plane[(td2 + a) * SP + td3 + c2];

        // w1 plain: w1[c][0][kd0][kd1][kd2][kd3]
        #pragma unroll
        for (int c = 0; c < 8; ++c) {
            const float* wp = w1 + ((c * 5 + kd0) * 5 + kd1) * 25;
            float s = 0.f;
            #pragma unroll
            for (int t = 0; t < 25; ++t) s += v[t] * wp[t];
            accP[8 + c] += s;
        }
        // w1 swapped: w1[c][0][kd2][kd3][kd0][kd1]
        #pragma unroll
        for (int c = 0; c < 8; ++c) {
            const float* wp = w1 + c * 625 + kd0 * 5 + kd1;
            float s = 0.f;
            #pragma unroll
            for (int t = 0; t < 25; ++t) s += v[t] * wp[t * 25];
            accS[8 + c] += s;
        }
        // w0 plain (3,3,5,5): only when kd0,kd1 in [1,3]
        if (kd0 >= 1 && kd0 <= 3 && kd1 >= 1 && kd1 <= 3) {
            #pragma unroll
            for (int c = 0; c < 8; ++c) {
                const float* wp = w0 + ((c * 3 + (kd0 - 1)) * 3 + (kd1 - 1)) * 25;
                float s = 0.f;
                #pragma unroll
                for (int t = 0; t < 25; ++t) s += v[t] * wp[t];
                accP[c] += s;
            }
        }
        // w0 swapped (5,5,3,3): taps (kd2,kd3) in 3x3, offsets +-1
        #pragma unroll
        for (int c = 0; c < 8; ++c) {
            const float* wp = w0 + c * 225 + kd0 * 5 + kd1;
            float s = 0.f;
            #pragma unroll
            for (int t2 = 0; t2 < 3; ++t2)
                #pragma unroll
                for (int t3 = 0; t3 < 3; ++t3)
                    s += v[(t2 + 1) * 5 + (t3 + 1)] * wp[(t2 * 3 + t3) * 25];
            accS[c] += s;
        }
    }
    if (!active) return;
    const int p = d01 * PLANE + tid;  // tid = td2*25+td3
    float* hb = h + (size_t)b * 16 * VOL;
    #pragma unroll
    for (int c = 0; c < 16; ++c) {
        float bias = (c < 8) ? b0[c] : b1[c - 8];
        hb[(size_t)c * VOL + p] = fmaxf(accP[c] + bias, 0.f) + fmaxf(accS[c] + bias, 0.f);
    }
}

// 16->16 conv, k=5^4, relu+bias. Register-tiled: 128 threads, thread (gq,c)
// computes 5 outputs d2=gq*5..gq*5+4 at d3=c for ALL 16 co.
// Weights for (ci,k01) staged in LDS (SWAP absorbed into staging gather),
// read back as broadcast ds_read_b128. 2000 FMA / ~157 LDS reads per iter.
template <int SWAP>
__global__ __launch_bounds__(128) void conv16x16_v2(
    const float* __restrict__ in, const float* __restrict__ w,
    const float* __restrict__ bias, float* __restrict__ out)
{
    __shared__ float plane[SP * SP];
    __shared__ __align__(16) float wlds[16 * 28];
    const int blk = blockIdx.x;
    const int b = blk / PLANE;
    const int d01 = blk - b * PLANE;
    const int d0 = d01 / S, d1 = d01 - d0 * S;
    const int tid = threadIdx.x;
    const int gq = tid / 25, c = tid - gq * 25;
    const bool active = tid < 125;

    float acc[16][5];
    #pragma unroll
    for (int i = 0; i < 16; ++i)
        #pragma unroll
        for (int r = 0; r < 5; ++r) acc[i][r] = 0.f;

    #pragma unroll 1
    for (int ci = 0; ci < 16; ++ci) {
        const float* inb = in + ((size_t)b * 16 + ci) * VOL;
        #pragma unroll 1
        for (int k01 = 0; k01 < 25; ++k01) {
            const int kd0 = k01 / 5, kd1 = k01 - kd0 * 5;
            const int e0 = d0 + kd0 - 2, e1 = d1 + kd1 - 2;
            const bool inr = (e0 >= 0 && e0 < S && e1 >= 0 && e1 < S);
            __syncthreads();
            if (inr) {
                stage_plane_n(inb + (e0 * S + e1) * PLANE, plane, tid, 128);
                for (int i = tid; i < 400; i += 128) {
                    const int co = i / 25, t = i - co * 25;
                    wlds[co * 28 + t] = SWAP
                        ? w[(co * 16 + ci) * 625 + t * 25 + k01]
                        : w[(co * 16 + ci) * 625 + k01 * 25 + t];
                }
            }
            __syncthreads();
            if (!inr || !active) continue;

            float v[45];
            #pragma unroll
            for (int rr = 0; rr < 9; ++rr)
                #pragma unroll
                for (int cc = 0; cc < 5; ++cc)
                    v[rr * 5 + cc] = plane[(gq * 5 + rr) * SP + c + cc];

            #pragma unroll
            for (int co = 0; co < 16; ++co) {
                float wr[28];
                const float4* wv4 = (const float4*)&wlds[co * 28];
                #pragma unroll
                for (int j = 0; j < 7; ++j) *(float4*)&wr[4 * j] = wv4[j];
                #pragma unroll
                for (int r = 0; r < 5; ++r)
                    #pragma unroll
                    for (int k2 = 0; k2 < 5; ++k2)
                        #pragma unroll
                        for (int k3 = 0; k3 < 5; ++k3)
                            acc[co][r] += v[(r + k2) * 5 + k3] * wr[k2 * 5 + k3];
            }
        }
    }
    if (!active) return;
    float* ob = out + (size_t)b * 16 * VOL;
    #pragma unroll
    for (int co = 0; co < 16; ++co) {
        const float bv = bias[co];
        #pragma unroll
        for (int r = 0; r < 5; ++r) {
            const int p = d01 * PLANE + (gq * 5 + r) * S + c;
            ob[(size_t)co * VOL + p] = fmaxf(acc[co][r] + bv, 0.f);
        }
    }
}

// 16->1 conv, k=5^4, relu+bias, optional accumulate into out.
// Same register-window structure; weights (25/iter) staged in LDS.
template <int SWAP, int ADD>
__global__ __launch_bounds__(128) void conv16x1_v2(
    const float* __restrict__ g, const float* __restrict__ w,
    const float* __restrict__ bias, float* __restrict__ out)
{
    __shared__ float plane[SP * SP];
    __shared__ __align__(16) float wlds[28];
    const int blk = blockIdx.x;
    const int b = blk / PLANE;
    const int d01 = blk - b * PLANE;
    const int d0 = d01 / S, d1 = d01 - d0 * S;
    const int tid = threadIdx.x;
    const int gq = tid / 25, c = tid - gq * 25;
    const bool active = tid < 125;

    float acc[5];
    #pragma unroll
    for (int r = 0; r < 5; ++r) acc[r] = 0.f;

    #pragma unroll 1
    for (int ci = 0; ci < 16; ++ci) {
        const float* gb = g + ((size_t)b * 16 + ci) * VOL;
        #pragma unroll 1
        for (int k01 = 0; k01 < 25; ++k01) {
            const int kd0 = k01 / 5, kd1 = k01 - kd0 * 5;
            const int e0 = d0 + kd0 - 2, e1 = d1 + kd1 - 2;
            const bool inr = (e0 >= 0 && e0 < S && e1 >= 0 && e1 < S);
            __syncthreads();
            if (inr) {
                stage_plane_n(gb + (e0 * S + e1) * PLANE, plane, tid, 128);
                if (tid < 25)
                    wlds[tid] = SWAP ? w[ci * 625 + tid * 25 + k01]
                                     : w[ci * 625 + k01 * 25 + tid];
            }
            __syncthreads();
            if (!inr || !active) continue;

            float v[45];
            #pragma unroll
            for (int rr = 0; rr < 9; ++rr)
                #pragma unroll
                for (int cc = 0; cc < 5; ++cc)
                    v[rr * 5 + cc] = plane[(gq * 5 + rr) * SP + c + cc];

            float wr[28];
            const float4* wv4 = (const float4*)&wlds[0];
            #pragma unroll
            for (int j = 0; j < 7; ++j) *(float4*)&wr[4 * j] = wv4[j];

            #pragma unroll
            for (int r = 0; r < 5; ++r)
                #pragma unroll
                for (int k2 = 0; k2 < 5; ++k2)
                    #pragma unroll
                    for (int k3 = 0; k3 < 5; ++k3)
                        acc[r] += v[(r + k2) * 5 + k3] * wr[k2 * 5 + k3];
        }
    }
    if (!active) return;
    const float bv = bias[0];
    #pragma unroll
    for (int r = 0; r < 5; ++r) {
        const int p = d01 * PLANE + (gq * 5 + r) * S + c;
        const float val = fmaxf(acc[r] + bv, 0.f);
        if (ADD) out[(size_t)b * VOL + p] += val;
        else     out[(size_t)b * VOL + p] = val;
    }
}

extern "C" void kernel_launch(void* const* d_in, const int* in_sizes, int n_in,
                              void* d_out, int out_size, void* d_ws, size_t ws_size,
                              hipStream_t stream) {
    const float* x   = (const float*)d_in[0];
    const float* w0  = (const float*)d_in[1];
    const float* b0  = (const float*)d_in[2];
    const float* w1  = (const float*)d_in[3];
    const float* b1  = (const float*)d_in[4];
    const float* w2a = (const float*)d_in[5];
    const float* b2a = (const float*)d_in[6];
    const float* w2b = (const float*)d_in[7];
    const float* b2b = (const float*)d_in[8];
    float* out = (float*)d_out;

    const size_t hvol = (size_t)2 * 16 * VOL;   // 12.5M floats = 50 MB
    if (ws_size < 2 * hvol * sizeof(float)) return;  // need h + g = 100 MB
    float* h = (float*)d_ws;
    float* g = h + hvol;

    const int nblk = 2 * PLANE;  // 1250

    layer1_kernel<<<nblk, 640, 0, stream>>>(x, w0, b0, w1, b1, h);

    // path A (plain weights): h -> g -> out (store)
    conv16x16_v2<0><<<nblk, 128, 0, stream>>>(h, w2a, b2a, g);
    conv16x1_v2<0, 0><<<nblk, 128, 0, stream>>>(g, w2b, b2b, out);

    // path B (pair-swapped weights): h -> g -> out (accumulate)
    conv16x16_v2<1><<<nblk, 128, 0, stream>>>(h, w2a, b2a, g);
    conv16x1_v2<1, 1><<<nblk, 128, 0, stream>>>(g, w2b, b2b, out);
}

// Round 3
// 2186.459 us; speedup vs baseline: 9.3766x; 8.5759x over previous
//
#include <hip/hip_runtime.h>

#define S 25
#define SP 29
#define PLANE 625
#define VOL 390625

typedef __attribute__((ext_vector_type(8))) short short8;
typedef __attribute__((ext_vector_type(4))) float f32x4;
typedef __attribute__((ext_vector_type(4))) unsigned short us4;
typedef __attribute__((ext_vector_type(4))) unsigned int u32x4;

__device__ __forceinline__ unsigned short f2bf(float f) {
    unsigned int u = __float_as_uint(f);
    u += 0x7fffu + ((u >> 16) & 1u);
    return (unsigned short)(u >> 16);
}

// ---------------- weight prep: reshape to MFMA A-fragment layout, bf16 -----
// wbig[kd01][pair13][tile2][co16][k32], k = tp*16+ci, tap t=2*pair+tp (t>24 -> 0)
//   tile0: plain  w2a[co][ci][kd0][kd1][kd2][kd3]
//   tile1: swap   w2a[co][ci][kd2][kd3][kd0][kd1]
// wbc[var2][kd01][pair13][k32] from w2b (co=1), var0 plain / var1 swap
__global__ __launch_bounds__(256) void prep_weights(
    const float* __restrict__ w2a, const float* __restrict__ w2b,
    unsigned short* __restrict__ wbig, unsigned short* __restrict__ wbc)
{
    int idx = blockIdx.x * 256 + threadIdx.x;
    if (idx < 332800) {
        int k = idx & 31;
        int co = (idx >> 5) & 15;
        int tile = (idx >> 9) & 1;
        int rem = idx >> 10;            // kd01*13 + pair
        int pr = rem % 13, kd01 = rem / 13;
        int t = 2 * pr + (k >> 4), ci = k & 15;
        float v = 0.f;
        if (t <= 24)
            v = (tile == 0) ? w2a[(co * 16 + ci) * 625 + kd01 * 25 + t]
                            : w2a[(co * 16 + ci) * 625 + t * 25 + kd01];
        wbig[idx] = f2bf(v);
    } else if (idx < 332800 + 20800) {
        int j = idx - 332800;
        int var = j / 10400, r = j % 10400;
        int k = r & 31;
        int rem = r >> 5;               // kd01*13 + pair
        int pr = rem % 13, kd01 = rem / 13;
        int t = 2 * pr + (k >> 4), ci = k & 15;
        float v = 0.f;
        if (t <= 24)
            v = (var == 0) ? w2b[ci * 625 + kd01 * 25 + t]
                           : w2b[ci * 625 + t * 25 + kd01];
        wbc[j] = f2bf(v);
    }
}

// ---------------- layer 1 (f32 VALU), writes h channels-last bf16 ----------
__device__ __forceinline__ void stage_plane_n(const float* __restrict__ src,
                                              float* plane, int tid, int nthr)
{
    for (int i = tid; i < SP * SP; i += nthr) {
        int r = i / SP, c = i - r * SP;
        int d2e = r - 2, d3e = c - 2;
        float v = 0.f;
        if (d2e >= 0 && d2e < S && d3e >= 0 && d3e < S) v = src[d2e * S + d3e];
        plane[i] = v;
    }
}

__global__ __launch_bounds__(640) void layer1_kernel(
    const float* __restrict__ x,
    const float* __restrict__ w0, const float* __restrict__ b0,
    const float* __restrict__ w1, const float* __restrict__ b1,
    unsigned short* __restrict__ hbf)
{
    __shared__ float plane[SP * SP];
    const int blk = blockIdx.x;
    const int b = blk / PLANE;
    const int d01 = blk - b * PLANE;
    const int d0 = d01 / S, d1 = d01 - d0 * S;
    const int tid = threadIdx.x;
    const int td2 = tid / S, td3 = tid - td2 * S;
    const bool active = tid < PLANE;

    float accP[16], accS[16];
    #pragma unroll
    for (int c = 0; c < 16; ++c) { accP[c] = 0.f; accS[c] = 0.f; }

    const float* xb = x + (size_t)b * VOL;

    #pragma unroll 1
    for (int k01 = 0; k01 < 25; ++k01) {
        const int kd0 = k01 / 5, kd1 = k01 - kd0 * 5;
        const int e0 = d0 + kd0 - 2, e1 = d1 + kd1 - 2;
        const bool inr = (e0 >= 0 && e0 < S && e1 >= 0 && e1 < S);
        __syncthreads();
        if (inr) stage_plane_n(xb + (e0 * S + e1) * PLANE, plane, tid, 640);
        __syncthreads();
        if (!inr || !active) continue;

        float v[25];
        #pragma unroll
        for (int a = 0; a < 5; ++a)
            #pragma unroll
            for (int c2 = 0; c2 < 5; ++c2)
                v[a * 5 + c2] = plane[(td2 + a) * SP + td3 + c2];

        #pragma unroll
        for (int c = 0; c < 8; ++c) {
            const float* wp = w1 + ((c * 5 + kd0) * 5 + kd1) * 25;
            float s = 0.f;
            #pragma unroll
            for (int t = 0; t < 25; ++t) s += v[t] * wp[t];
            accP[8 + c] += s;
        }
        #pragma unroll
        for (int c = 0; c < 8; ++c) {
            const float* wp = w1 + c * 625 + kd0 * 5 + kd1;
            float s = 0.f;
            #pragma unroll
            for (int t = 0; t < 25; ++t) s += v[t] * wp[t * 25];
            accS[8 + c] += s;
        }
        if (kd0 >= 1 && kd0 <= 3 && kd1 >= 1 && kd1 <= 3) {
            #pragma unroll
            for (int c = 0; c < 8; ++c) {
                const float* wp = w0 + ((c * 3 + (kd0 - 1)) * 3 + (kd1 - 1)) * 25;
                float s = 0.f;
                #pragma unroll
                for (int t = 0; t < 25; ++t) s += v[t] * wp[t];
                accP[c] += s;
            }
        }
        #pragma unroll
        for (int c = 0; c < 8; ++c) {
            const float* wp = w0 + c * 225 + kd0 * 5 + kd1;
            float s = 0.f;
            #pragma unroll
            for (int t2 = 0; t2 < 3; ++t2)
                #pragma unroll
                for (int t3 = 0; t3 < 3; ++t3)
                    s += v[(t2 + 1) * 5 + (t3 + 1)] * wp[(t2 * 3 + t3) * 25];
            accS[c] += s;
        }
    }
    if (!active) return;
    unsigned short* hb = hbf + ((size_t)(b * 625 + d01) * 625 + tid) * 16;
    #pragma unroll
    for (int q = 0; q < 4; ++q) {
        us4 u;
        #pragma unroll
        for (int r = 0; r < 4; ++r) {
            int c = q * 4 + r;
            float bias = (c < 8) ? b0[c] : b1[c - 8];
            u[r] = f2bf(fmaxf(accP[c] + bias, 0.f) + fmaxf(accS[c] + bias, 0.f));
        }
        *(us4*)&hb[q * 4] = u;
    }
}

// ---------------- implicit-GEMM MFMA conv (16->16 fused pair, or 16->1) ----
// Block = (b, d0, d1). LDS plane: [29*29 pts][24 ushort] (ci0-7 @0, ci8-15 @8,
// pad @16 -> 48B rows). MFMA 16x16x32: K = tap-pair(2) x ci(16), N = 16 points.
// NTILE=2: A tiles = {plain co16, swap co16} from wbig; writes gA,gB (bf16 CL).
// NTILE=1: A row0 = w2b (wq = wbc variant); writes f32 out (ADD accumulates).
template <int NTILE, int ADD>
__global__ __launch_bounds__(256) void conv_mfma(
    const unsigned short* __restrict__ in, const unsigned short* __restrict__ wq,
    const float* __restrict__ bias,
    unsigned short* __restrict__ gA, unsigned short* __restrict__ gB,
    float* __restrict__ outp)
{
    __shared__ __align__(16) unsigned short pl[841 * 24];
    const int blk = blockIdx.x;
    const int b = blk / PLANE;
    const int d01 = blk - b * PLANE;
    const int d0 = d01 / S, d1 = d01 - d0 * S;
    const int tid = threadIdx.x;
    const int l = tid & 63, w = tid >> 6;
    const int tp = l >> 5;               // tap-in-pair
    const int kq = (l >> 4) & 3;         // k-group 0..3
    const int h8 = (kq & 1) * 8;         // ci-half offset (ushorts)
    const int col = l & 15;              // N column

    int rb24[10];
    #pragma unroll
    for (int g = 0; g < 10; ++g) {
        int n = (w * 10 + g) * 16 + col;
        if (n > 624) n = 624;
        int d2 = n / 25, d3 = n - d2 * 25;
        rb24[g] = (d2 * 29 + d3) * 24;
    }

    f32x4 acc[10][NTILE];
    #pragma unroll
    for (int g = 0; g < 10; ++g)
        #pragma unroll
        for (int t = 0; t < NTILE; ++t)
            acc[g][t] = (f32x4){0.f, 0.f, 0.f, 0.f};

    #pragma unroll 1
    for (int kd01 = 0; kd01 < 25; ++kd01) {
        const int kd0 = kd01 / 5, kd1 = kd01 - kd0 * 5;
        const int e0 = d0 + kd0 - 2, e1 = d1 + kd1 - 2;
        if (e0 < 0 || e0 >= S || e1 < 0 || e1 >= S) continue;  // block-uniform

        __syncthreads();
        {   // stage 29x29 halo plane, channels-last bf16, 16B chunks
            const unsigned short* srcp = in + (size_t)(b * 625 + e0 * 25 + e1) * 625 * 16;
            for (int cid = tid; cid < 1682; cid += 256) {       // 29*58
                int r = cid / 58, w8 = cid - r * 58;
                int c = w8 >> 1, hh = w8 & 1;
                u32x4 v = {0u, 0u, 0u, 0u};
                if (r >= 2 && r <= 26 && c >= 2 && c <= 26)
                    v = *(const u32x4*)(srcp + (((r - 2) * 25) + (c - 2)) * 16 + hh * 8);
                *(u32x4*)&pl[(r * 29 + c) * 24 + hh * 8] = v;
            }
        }
        __syncthreads();

        #pragma unroll 1
        for (int pr = 0; pr < 13; ++pr) {
            short8 a0, a1;
            if (NTILE == 2) {
                const unsigned short* wp = wq + (size_t)kd01 * 13312 + pr * 1024;
                a0 = *(const short8*)(wp + col * 32 + kq * 8);
                a1 = *(const short8*)(wp + 512 + col * 32 + kq * 8);
            } else {
                short8 z = {0, 0, 0, 0, 0, 0, 0, 0};
                a0 = z;
                if (col == 0)
                    a0 = *(const short8*)(wq + kd01 * 416 + pr * 32 + kq * 8);
                a1 = z;
            }
            int t = 2 * pr + tp;
            if (t > 24) t = 24;
            int t5 = t / 5;
            int aofs = (t5 * 29 + (t - t5 * 5)) * 24 + h8;
            #pragma unroll
            for (int g = 0; g < 10; ++g) {
                short8 bfrag = *(const short8*)&pl[rb24[g] + aofs];
                acc[g][0] = __builtin_amdgcn_mfma_f32_16x16x32_bf16(a0, bfrag, acc[g][0], 0, 0, 0);
                if (NTILE == 2)
                    acc[g][1] = __builtin_amdgcn_mfma_f32_16x16x32_bf16(a1, bfrag, acc[g][1], 0, 0, 0);
            }
        }
    }

    // epilogue: C layout col=lane&15 (point), row=(lane>>4)*4+reg (co)
    if (NTILE == 2) {
        const int cob = kq * 4;
        float bi[4];
        #pragma unroll
        for (int r = 0; r < 4; ++r) bi[r] = bias[cob + r];
        #pragma unroll
        for (int g = 0; g < 10; ++g) {
            int n = (w * 10 + g) * 16 + col;
            if (n < 625) {
                size_t ob = ((size_t)(b * 625 + d01) * 625 + n) * 16 + cob;
                us4 ua, ub;
                #pragma unroll
                for (int r = 0; r < 4; ++r) {
                    ua[r] = f2bf(fmaxf(acc[g][0][r] + bi[r], 0.f));
                    ub[r] = f2bf(fmaxf(acc[g][1][r] + bi[r], 0.f));
                }
                *(us4*)&gA[ob] = ua;
                *(us4*)&gB[ob] = ub;
            }
        }
    } else {
        if (kq == 0) {  // C row 0 lives in reg 0 of lanes l>>4==0
            const float bv = bias[0];
            #pragma unroll
            for (int g = 0; g < 10; ++g) {
                int n = (w * 10 + g) * 16 + col;
                if (n < 625) {
                    float v = fmaxf(acc[g][0][0] + bv, 0.f);
                    size_t oi = (size_t)b * VOL + (size_t)d01 * 625 + n;
                    if (ADD) outp[oi] += v;
                    else     outp[oi] = v;
                }
            }
        }
    }
}

extern "C" void kernel_launch(void* const* d_in, const int* in_sizes, int n_in,
                              void* d_out, int out_size, void* d_ws, size_t ws_size,
                              hipStream_t stream) {
    const float* x   = (const float*)d_in[0];
    const float* w0  = (const float*)d_in[1];
    const float* b0  = (const float*)d_in[2];
    const float* w1  = (const float*)d_in[3];
    const float* b1  = (const float*)d_in[4];
    const float* w2a = (const float*)d_in[5];
    const float* b2a = (const float*)d_in[6];
    const float* w2b = (const float*)d_in[7];
    const float* b2b = (const float*)d_in[8];
    float* out = (float*)d_out;

    // ws layout (ushort units): hbf | gA | gB | wbig | wbc
    const size_t CL = (size_t)2 * 625 * 625 * 16;   // 12.5M ushorts per buffer
    unsigned short* hbf  = (unsigned short*)d_ws;
    unsigned short* gA   = hbf + CL;
    unsigned short* gB   = gA + CL;
    unsigned short* wbig = gB + CL;                  // 332800
    unsigned short* wbc  = wbig + 332800;            // 2*10400
    if (ws_size < (3 * CL + 332800 + 20800) * sizeof(unsigned short)) return;

    const int nblk = 2 * PLANE;  // 1250

    prep_weights<<<1382, 256, 0, stream>>>(w2a, w2b, wbig, wbc);
    layer1_kernel<<<nblk, 640, 0, stream>>>(x, w0, b0, w1, b1, hbf);

    // fused conv2a: both paths in one pass -> gA (plain), gB (swap)
    conv_mfma<2, 0><<<nblk, 256, 0, stream>>>(hbf, wbig, b2a, gA, gB, nullptr);
    // conv2b: path A stores, path B accumulates
    conv_mfma<1, 0><<<nblk, 256, 0, stream>>>(gA, wbc,         b2b, nullptr, nullptr, out);
    conv_mfma<1, 1><<<nblk, 256, 0, stream>>>(gB, wbc + 10400, b2b, nullptr, nullptr, out);
}

// Round 4
// 1447.679 us; speedup vs baseline: 14.1617x; 1.5103x over previous
//
#include <hip/hip_runtime.h>

#define S 25
#define SP 29
#define PLANE 625
#define VOL 390625

typedef __attribute__((ext_vector_type(8))) short short8;
typedef __attribute__((ext_vector_type(4))) float f32x4;
typedef __attribute__((ext_vector_type(4))) unsigned short us4;
typedef __attribute__((ext_vector_type(4))) unsigned int u32x4;

__device__ __forceinline__ unsigned short f2bf(float f) {
    unsigned int u = __float_as_uint(f);
    u += 0x7fffu + ((u >> 16) & 1u);
    return (unsigned short)(u >> 16);
}

// ---------------- weight prep ---------------------------------------------
// wbig[kd01][pair13][tile2][co16][k32], k = tp*16+ci (conv16x16, as round 3)
// wcb2[kd01][t25][row2][k32]: row0 = plain w2b on gA slots (k<16),
//                             row1 = swap  w2b on gB slots (k>=16)
// wl1 [kd01][tile2][row16][k32]: k = tap t (25 real + 7 pad)
//   tile0: rows 0-7 w1 plain co, rows 8-15 w1 swap co   (-> h ch 8..15)
//   tile1: rows 0-7 w0 plain co, rows 8-15 w0 swap co   (-> h ch 0..7)
__global__ __launch_bounds__(256) void prep_weights(
    const float* __restrict__ w2a, const float* __restrict__ w2b,
    const float* __restrict__ w0, const float* __restrict__ w1,
    unsigned short* __restrict__ wbig, unsigned short* __restrict__ wcb2,
    unsigned short* __restrict__ wl1)
{
    int idx = blockIdx.x * 256 + threadIdx.x;
    if (idx < 332800) {
        int k = idx & 31;
        int co = (idx >> 5) & 15;
        int tile = (idx >> 9) & 1;
        int rem = idx >> 10;            // kd01*13 + pair
        int pr = rem % 13, kd01 = rem / 13;
        int t = 2 * pr + (k >> 4), ci = k & 15;
        float v = 0.f;
        if (t <= 24)
            v = (tile == 0) ? w2a[(co * 16 + ci) * 625 + kd01 * 25 + t]
                            : w2a[(co * 16 + ci) * 625 + t * 25 + kd01];
        wbig[idx] = f2bf(v);
    } else if (idx < 332800 + 40000) {
        int j = idx - 332800;
        int k = j & 31;
        int row = (j >> 5) & 1;
        int rem = j >> 6;               // kd01*25 + t
        int t = rem % 25, kd01 = rem / 25;
        float v = 0.f;
        if (row == 0) { if (k < 16)  v = w2b[k * 625 + kd01 * 25 + t]; }
        else          { if (k >= 16) v = w2b[(k - 16) * 625 + t * 25 + kd01]; }
        wcb2[j] = f2bf(v);
    } else if (idx < 332800 + 40000 + 25600) {
        int j = idx - 372800;
        int k = j & 31;
        int row = (j >> 5) & 15;
        int tile = (j >> 9) & 1;
        int kd01 = j >> 10;
        int kd0 = kd01 / 5, kd1 = kd01 - kd0 * 5;
        float v = 0.f;
        if (k < 25) {
            int t = k, kd2 = t / 5, kd3 = t - kd2 * 5;
            if (tile == 0) {
                v = (row < 8) ? w1[row * 625 + kd0 * 125 + kd1 * 25 + t]
                              : w1[(row - 8) * 625 + t * 25 + kd01];
            } else {
                if (row < 8) {
                    if (kd0 >= 1 && kd0 <= 3 && kd1 >= 1 && kd1 <= 3)
                        v = w0[((row * 3 + (kd0 - 1)) * 3 + (kd1 - 1)) * 25 + t];
                } else {
                    if (kd2 >= 1 && kd2 <= 3 && kd3 >= 1 && kd3 <= 3)
                        v = w0[(row - 8) * 225 + ((kd2 - 1) * 3 + (kd3 - 1)) * 25 + kd01];
                }
            }
        }
        wl1[j] = f2bf(v);
    }
}

// ---------------- layer 1, MFMA over taps ----------------------------------
// Block=(b,d0,d1). K=32 tap slots of the (kd2,kd3) plane. Two M-tiles (w1,w0),
// each 16 rows = 8 plain co + 8 swap co. relu-combine via shfl_xor(32).
__global__ __launch_bounds__(256) void layer1_mfma(
    const float* __restrict__ x, const unsigned short* __restrict__ wl1,
    const float* __restrict__ b0, const float* __restrict__ b1,
    unsigned short* __restrict__ hbf)
{
    __shared__ __align__(16) unsigned short pl[29 * 32];
    const int blk = blockIdx.x;
    const int b = blk / PLANE;
    const int d01 = blk - b * PLANE;
    const int d0 = d01 / S, d1 = d01 - d0 * S;
    const int tid = threadIdx.x;
    const int l = tid & 63, w = tid >> 6;
    const int col = l & 15, kq = l >> 4;

    int off[8];
    #pragma unroll
    for (int j = 0; j < 8; ++j) {
        int t = kq * 8 + j; if (t > 24) t = 24;
        int t5 = t / 5;
        off[j] = t5 * 32 + (t - t5 * 5);
    }
    int rb[10];
    #pragma unroll
    for (int g = 0; g < 10; ++g) {
        int n = (w * 10 + g) * 16 + col; if (n > 624) n = 624;
        int d2 = n / 25;
        rb[g] = d2 * 32 + (n - d2 * 25);
    }

    f32x4 acc0[10], acc1[10];
    #pragma unroll
    for (int g = 0; g < 10; ++g) {
        acc0[g] = (f32x4){0.f, 0.f, 0.f, 0.f};
        acc1[g] = (f32x4){0.f, 0.f, 0.f, 0.f};
    }

    const float* xb = x + (size_t)b * VOL;

    #pragma unroll 1
    for (int kd01 = 0; kd01 < 25; ++kd01) {
        const int kd0 = kd01 / 5, kd1 = kd01 - kd0 * 5;
        const int e0 = d0 + kd0 - 2, e1 = d1 + kd1 - 2;
        if (e0 < 0 || e0 >= S || e1 < 0 || e1 >= S) continue;  // block-uniform
        __syncthreads();
        {
            const float* sp = xb + (e0 * 25 + e1) * 625;
            for (int i = tid; i < 841; i += 256) {
                int r = i / 29, c = i - r * 29;
                float v = 0.f;
                if (r >= 2 && r <= 26 && c >= 2 && c <= 26)
                    v = sp[(r - 2) * 25 + (c - 2)];
                pl[r * 32 + c] = f2bf(v);
            }
        }
        __syncthreads();
        const unsigned short* wp = wl1 + kd01 * 1024;
        short8 a0 = *(const short8*)(wp + col * 32 + kq * 8);
        short8 a1 = *(const short8*)(wp + 512 + col * 32 + kq * 8);
        #pragma unroll
        for (int g = 0; g < 10; ++g) {
            short8 bf;
            #pragma unroll
            for (int j = 0; j < 8; ++j)
                bf[j] = (short)pl[rb[g] + off[j]];
            acc0[g] = __builtin_amdgcn_mfma_f32_16x16x32_bf16(a0, bf, acc0[g], 0, 0, 0);
            acc1[g] = __builtin_amdgcn_mfma_f32_16x16x32_bf16(a1, bf, acc1[g], 0, 0, 0);
        }
    }

    // epilogue: row = kq*4+r. kq<2: plain rows, partner (swap) at lane^32.
    const int ch = (kq & 1) * 4;
    float bi1[4], bi0[4];
    #pragma unroll
    for (int r = 0; r < 4; ++r) { bi1[r] = b1[ch + r]; bi0[r] = b0[ch + r]; }
    const bool lo = (kq < 2);
    const size_t obase = (size_t)(b * 625 + d01) * 625;
    #pragma unroll
    for (int g = 0; g < 10; ++g) {
        int n = (w * 10 + g) * 16 + col;
        float r0[4], r1[4];
        #pragma unroll
        for (int r = 0; r < 4; ++r) {
            r0[r] = fmaxf(acc0[g][r] + bi1[r], 0.f);   // tile0 = w1 -> b1
            r1[r] = fmaxf(acc1[g][r] + bi0[r], 0.f);   // tile1 = w0 -> b0
        }
        us4 u0, u1;
        #pragma unroll
        for (int r = 0; r < 4; ++r) {
            float p0 = __shfl_xor(r0[r], 32, 64);
            float p1 = __shfl_xor(r1[r], 32, 64);
            u0[r] = f2bf(r0[r] + p0);
            u1[r] = f2bf(r1[r] + p1);
        }
        if (lo && n < 625) {
            *(us4*)&hbf[(obase + n) * 16 + 8 + ch] = u0;  // w1 -> ch 8..15
            *(us4*)&hbf[(obase + n) * 16 + ch]     = u1;  // w0 -> ch 0..7
        }
    }
}

// ---------------- conv16x16 fused pair (unchanged from round 3) ------------
template <int NTILE, int ADD>
__global__ __launch_bounds__(256) void conv_mfma(
    const unsigned short* __restrict__ in, const unsigned short* __restrict__ wq,
    const float* __restrict__ bias,
    unsigned short* __restrict__ gA, unsigned short* __restrict__ gB,
    float* __restrict__ outp)
{
    __shared__ __align__(16) unsigned short pl[841 * 24];
    const int blk = blockIdx.x;
    const int b = blk / PLANE;
    const int d01 = blk - b * PLANE;
    const int d0 = d01 / S, d1 = d01 - d0 * S;
    const int tid = threadIdx.x;
    const int l = tid & 63, w = tid >> 6;
    const int tp = l >> 5;
    const int kq = (l >> 4) & 3;
    const int h8 = (kq & 1) * 8;
    const int col = l & 15;

    int rb24[10];
    #pragma unroll
    for (int g = 0; g < 10; ++g) {
        int n = (w * 10 + g) * 16 + col;
        if (n > 624) n = 624;
        int d2 = n / 25, d3 = n - d2 * 25;
        rb24[g] = (d2 * 29 + d3) * 24;
    }

    f32x4 acc[10][NTILE];
    #pragma unroll
    for (int g = 0; g < 10; ++g)
        #pragma unroll
        for (int t = 0; t < NTILE; ++t)
            acc[g][t] = (f32x4){0.f, 0.f, 0.f, 0.f};

    #pragma unroll 1
    for (int kd01 = 0; kd01 < 25; ++kd01) {
        const int kd0 = kd01 / 5, kd1 = kd01 - kd0 * 5;
        const int e0 = d0 + kd0 - 2, e1 = d1 + kd1 - 2;
        if (e0 < 0 || e0 >= S || e1 < 0 || e1 >= S) continue;

        __syncthreads();
        {
            const unsigned short* srcp = in + (size_t)(b * 625 + e0 * 25 + e1) * 625 * 16;
            for (int cid = tid; cid < 1682; cid += 256) {
                int r = cid / 58, w8 = cid - r * 58;
                int c = w8 >> 1, hh = w8 & 1;
                u32x4 v = {0u, 0u, 0u, 0u};
                if (r >= 2 && r <= 26 && c >= 2 && c <= 26)
                    v = *(const u32x4*)(srcp + (((r - 2) * 25) + (c - 2)) * 16 + hh * 8);
                *(u32x4*)&pl[(r * 29 + c) * 24 + hh * 8] = v;
            }
        }
        __syncthreads();

        #pragma unroll 1
        for (int pr = 0; pr < 13; ++pr) {
            short8 a0, a1;
            const unsigned short* wp = wq + (size_t)kd01 * 13312 + pr * 1024;
            a0 = *(const short8*)(wp + col * 32 + kq * 8);
            a1 = *(const short8*)(wp + 512 + col * 32 + kq * 8);
            int t = 2 * pr + tp;
            if (t > 24) t = 24;
            int t5 = t / 5;
            int aofs = (t5 * 29 + (t - t5 * 5)) * 24 + h8;
            #pragma unroll
            for (int g = 0; g < 10; ++g) {
                short8 bfrag = *(const short8*)&pl[rb24[g] + aofs];
                acc[g][0] = __builtin_amdgcn_mfma_f32_16x16x32_bf16(a0, bfrag, acc[g][0], 0, 0, 0);
                acc[g][1] = __builtin_amdgcn_mfma_f32_16x16x32_bf16(a1, bfrag, acc[g][1], 0, 0, 0);
            }
        }
    }

    const int cob = kq * 4;
    float bi[4];
    #pragma unroll
    for (int r = 0; r < 4; ++r) bi[r] = bias[cob + r];
    #pragma unroll
    for (int g = 0; g < 10; ++g) {
        int n = (w * 10 + g) * 16 + col;
        if (n < 625) {
            size_t ob = ((size_t)(b * 625 + d01) * 625 + n) * 16 + cob;
            us4 ua, ub;
            #pragma unroll
            for (int r = 0; r < 4; ++r) {
                ua[r] = f2bf(fmaxf(acc[g][0][r] + bi[r], 0.f));
                ub[r] = f2bf(fmaxf(acc[g][1][r] + bi[r], 0.f));
            }
            *(us4*)&gA[ob] = ua;
            *(us4*)&gB[ob] = ub;
        }
    }
}

// ---------------- fused conv16x1 pair --------------------------------------
// LDS [pt 29x29][32ch] = {gA ci16, gB ci16}. K=32. A row0 = plain on gA,
// row1 = swap on gB. out = relu(rowA+b)+relu(rowB+b), single f32 store.
__global__ __launch_bounds__(256) void convc_kernel(
    const unsigned short* __restrict__ gA, const unsigned short* __restrict__ gB,
    const unsigned short* __restrict__ wcb2, const float* __restrict__ b2b,
    float* __restrict__ outp)
{
    __shared__ __align__(16) unsigned short pl[841 * 32];
    const int blk = blockIdx.x;
    const int b = blk / PLANE;
    const int d01 = blk - b * PLANE;
    const int d0 = d01 / S, d1 = d01 - d0 * S;
    const int tid = threadIdx.x;
    const int l = tid & 63, w = tid >> 6;
    const int col = l & 15, kq = l >> 4;

    int rb[10];
    #pragma unroll
    for (int g = 0; g < 10; ++g) {
        int n = (w * 10 + g) * 16 + col; if (n > 624) n = 624;
        int d2 = n / 25;
        rb[g] = d2 * 29 + (n - d2 * 25);
    }

    f32x4 acc[10];
    #pragma unroll
    for (int g = 0; g < 10; ++g) acc[g] = (f32x4){0.f, 0.f, 0.f, 0.f};

    #pragma unroll 1
    for (int kd01 = 0; kd01 < 25; ++kd01) {
        const int kd0 = kd01 / 5, kd1 = kd01 - kd0 * 5;
        const int e0 = d0 + kd0 - 2, e1 = d1 + kd1 - 2;
        if (e0 < 0 || e0 >= S || e1 < 0 || e1 >= S) continue;

        __syncthreads();
        {
            const size_t sb = ((size_t)(b * 625 + e0 * 25 + e1)) * 625 * 16;
            #pragma unroll
            for (int buf = 0; buf < 2; ++buf) {
                const unsigned short* src = (buf ? gB : gA) + sb;
                for (int cid = tid; cid < 1682; cid += 256) {
                    int p = cid >> 1, hh = cid & 1;
                    int r = p / 29, c = p - r * 29;
                    u32x4 v = {0u, 0u, 0u, 0u};
                    if (r >= 2 && r <= 26 && c >= 2 && c <= 26)
                        v = *(const u32x4*)(src + ((r - 2) * 25 + (c - 2)) * 16 + hh * 8);
                    *(u32x4*)&pl[p * 32 + buf * 16 + hh * 8] = v;
                }
            }
        }
        __syncthreads();

        #pragma unroll 1
        for (int t = 0; t < 25; ++t) {
            const int t5 = t / 5;
            const int toff = t5 * 29 + (t - t5 * 5);
            short8 a = {0, 0, 0, 0, 0, 0, 0, 0};
            if (col < 2)
                a = *(const short8*)(wcb2 + ((kd01 * 25 + t) * 2 + col) * 32 + kq * 8);
            #pragma unroll
            for (int g = 0; g < 10; ++g) {
                short8 bf = *(const short8*)&pl[(rb[g] + toff) * 32 + kq * 8];
                acc[g] = __builtin_amdgcn_mfma_f32_16x16x32_bf16(a, bf, acc[g], 0, 0, 0);
            }
        }
    }

    if (kq == 0) {
        const float bv = b2b[0];
        #pragma unroll
        for (int g = 0; g < 10; ++g) {
            int n = (w * 10 + g) * 16 + col;
            if (n < 625)
                outp[(size_t)b * VOL + (size_t)d01 * 625 + n] =
                    fmaxf(acc[g][0] + bv, 0.f) + fmaxf(acc[g][1] + bv, 0.f);
        }
    }
}

extern "C" void kernel_launch(void* const* d_in, const int* in_sizes, int n_in,
                              void* d_out, int out_size, void* d_ws, size_t ws_size,
                              hipStream_t stream) {
    const float* x   = (const float*)d_in[0];
    const float* w0  = (const float*)d_in[1];
    const float* b0  = (const float*)d_in[2];
    const float* w1  = (const float*)d_in[3];
    const float* b1  = (const float*)d_in[4];
    const float* w2a = (const float*)d_in[5];
    const float* b2a = (const float*)d_in[6];
    const float* w2b = (const float*)d_in[7];
    const float* b2b = (const float*)d_in[8];
    float* out = (float*)d_out;

    // ws layout (ushort units): hbf | gA | gB | wbig | wcb2 | wl1
    const size_t CL = (size_t)2 * 625 * 625 * 16;
    unsigned short* hbf  = (unsigned short*)d_ws;
    unsigned short* gA   = hbf + CL;
    unsigned short* gB   = gA + CL;
    unsigned short* wbig = gB + CL;                  // 332800
    unsigned short* wcb2 = wbig + 332800;            // 40000
    unsigned short* wl1  = wcb2 + 40000;             // 25600
    if (ws_size < (3 * CL + 332800 + 40000 + 25600) * sizeof(unsigned short)) return;

    const int nblk = 2 * PLANE;  // 1250

    prep_weights<<<1557, 256, 0, stream>>>(w2a, w2b, w0, w1, wbig, wcb2, wl1);
    layer1_mfma<<<nblk, 256, 0, stream>>>(x, wl1, b0, b1, hbf);
    conv_mfma<2, 0><<<nblk, 256, 0, stream>>>(hbf, wbig, b2a, gA, gB, nullptr);
    convc_kernel<<<nblk, 256, 0, stream>>>(gA, gB, wcb2, b2b, out);
}

// Round 5
// 1118.373 us; speedup vs baseline: 18.3317x; 1.2945x over previous
//
#include <hip/hip_runtime.h>

#define S 25
#define SP 29
#define PLANE 625
#define VOL 390625

typedef __attribute__((ext_vector_type(8))) short short8;
typedef __attribute__((ext_vector_type(4))) float f32x4;
typedef __attribute__((ext_vector_type(4))) unsigned short us4;
typedef __attribute__((ext_vector_type(4))) unsigned int u32x4;

__device__ __forceinline__ unsigned short f2bf(float f) {
    unsigned int u = __float_as_uint(f);
    u += 0x7fffu + ((u >> 16) & 1u);
    return (unsigned short)(u >> 16);
}

// ---------------- weight prep ---------------------------------------------
// wbig[kd01][pair13][tile2][co16][k32], k = tp*16+ci (conv16x16)
// wl1 [kd01][tile2][row16][k32]: layer-1 taps (as round 4)
// wp2 [uv36][t25][row8][k32]: convc patch table. uv = u*6+v (slab offset),
//   row = (py*2+px)*2+path; kd0=u-py, kd1=v-px; path0 = plain on gA slots
//   (k<16), path1 = swap on gB slots (k>=16). Zero outside kernel range.
__global__ __launch_bounds__(256) void prep_weights(
    const float* __restrict__ w2a, const float* __restrict__ w2b,
    const float* __restrict__ w0, const float* __restrict__ w1,
    unsigned short* __restrict__ wbig, unsigned short* __restrict__ wl1,
    unsigned short* __restrict__ wp2)
{
    int idx = blockIdx.x * 256 + threadIdx.x;
    if (idx < 332800) {
        int k = idx & 31;
        int co = (idx >> 5) & 15;
        int tile = (idx >> 9) & 1;
        int rem = idx >> 10;            // kd01*13 + pair
        int pr = rem % 13, kd01 = rem / 13;
        int t = 2 * pr + (k >> 4), ci = k & 15;
        float v = 0.f;
        if (t <= 24)
            v = (tile == 0) ? w2a[(co * 16 + ci) * 625 + kd01 * 25 + t]
                            : w2a[(co * 16 + ci) * 625 + t * 25 + kd01];
        wbig[idx] = f2bf(v);
    } else if (idx < 332800 + 25600) {
        int j = idx - 332800;
        int k = j & 31;
        int row = (j >> 5) & 15;
        int tile = (j >> 9) & 1;
        int kd01 = j >> 10;
        int kd0 = kd01 / 5, kd1 = kd01 - kd0 * 5;
        float v = 0.f;
        if (k < 25) {
            int t = k, kd2 = t / 5, kd3 = t - kd2 * 5;
            if (tile == 0) {
                v = (row < 8) ? w1[row * 625 + kd0 * 125 + kd1 * 25 + t]
                              : w1[(row - 8) * 625 + t * 25 + kd01];
            } else {
                if (row < 8) {
                    if (kd0 >= 1 && kd0 <= 3 && kd1 >= 1 && kd1 <= 3)
                        v = w0[((row * 3 + (kd0 - 1)) * 3 + (kd1 - 1)) * 25 + t];
                } else {
                    if (kd2 >= 1 && kd2 <= 3 && kd3 >= 1 && kd3 <= 3)
                        v = w0[(row - 8) * 225 + ((kd2 - 1) * 3 + (kd3 - 1)) * 25 + kd01];
                }
            }
        }
        wl1[j] = f2bf(v);
    } else if (idx < 332800 + 25600 + 230400) {
        int j = idx - 358400;
        int k = j & 31;
        int row = (j >> 5) & 7;
        int rem = j >> 8;               // uv*25 + t
        int t = rem % 25, uv = rem / 25;
        int u = uv / 6, v6 = uv - u * 6;
        int path = row & 1, o = row >> 1;
        int py = o >> 1, px = o & 1;
        int kd0 = u - py, kd1 = v6 - px;
        float v = 0.f;
        if (kd0 >= 0 && kd0 < 5 && kd1 >= 0 && kd1 < 5) {
            int ci = k & 15;
            if (path == 0 && k < 16)
                v = w2b[ci * 625 + (kd0 * 5 + kd1) * 25 + t];
            else if (path == 1 && k >= 16)
                v = w2b[ci * 625 + t * 25 + kd0 * 5 + kd1];
        }
        wp2[j] = f2bf(v);
    }
}

// ---------------- layer 1, MFMA over taps (unchanged) ----------------------
__global__ __launch_bounds__(256) void layer1_mfma(
    const float* __restrict__ x, const unsigned short* __restrict__ wl1,
    const float* __restrict__ b0, const float* __restrict__ b1,
    unsigned short* __restrict__ hbf)
{
    __shared__ __align__(16) unsigned short pl[29 * 32];
    const int blk = blockIdx.x;
    const int b = blk / PLANE;
    const int d01 = blk - b * PLANE;
    const int d0 = d01 / S, d1 = d01 - d0 * S;
    const int tid = threadIdx.x;
    const int l = tid & 63, w = tid >> 6;
    const int col = l & 15, kq = l >> 4;

    int off[8];
    #pragma unroll
    for (int j = 0; j < 8; ++j) {
        int t = kq * 8 + j; if (t > 24) t = 24;
        int t5 = t / 5;
        off[j] = t5 * 32 + (t - t5 * 5);
    }
    int rb[10];
    #pragma unroll
    for (int g = 0; g < 10; ++g) {
        int n = (w * 10 + g) * 16 + col; if (n > 624) n = 624;
        int d2 = n / 25;
        rb[g] = d2 * 32 + (n - d2 * 25);
    }

    f32x4 acc0[10], acc1[10];
    #pragma unroll
    for (int g = 0; g < 10; ++g) {
        acc0[g] = (f32x4){0.f, 0.f, 0.f, 0.f};
        acc1[g] = (f32x4){0.f, 0.f, 0.f, 0.f};
    }

    const float* xb = x + (size_t)b * VOL;

    #pragma unroll 1
    for (int kd01 = 0; kd01 < 25; ++kd01) {
        const int kd0 = kd01 / 5, kd1 = kd01 - kd0 * 5;
        const int e0 = d0 + kd0 - 2, e1 = d1 + kd1 - 2;
        if (e0 < 0 || e0 >= S || e1 < 0 || e1 >= S) continue;
        __syncthreads();
        {
            const float* sp = xb + (e0 * 25 + e1) * 625;
            for (int i = tid; i < 841; i += 256) {
                int r = i / 29, c = i - r * 29;
                float v = 0.f;
                if (r >= 2 && r <= 26 && c >= 2 && c <= 26)
                    v = sp[(r - 2) * 25 + (c - 2)];
                pl[r * 32 + c] = f2bf(v);
            }
        }
        __syncthreads();
        const unsigned short* wp = wl1 + kd01 * 1024;
        short8 a0 = *(const short8*)(wp + col * 32 + kq * 8);
        short8 a1 = *(const short8*)(wp + 512 + col * 32 + kq * 8);
        #pragma unroll
        for (int g = 0; g < 10; ++g) {
            short8 bf;
            #pragma unroll
            for (int j = 0; j < 8; ++j)
                bf[j] = (short)pl[rb[g] + off[j]];
            acc0[g] = __builtin_amdgcn_mfma_f32_16x16x32_bf16(a0, bf, acc0[g], 0, 0, 0);
            acc1[g] = __builtin_amdgcn_mfma_f32_16x16x32_bf16(a1, bf, acc1[g], 0, 0, 0);
        }
    }

    const int ch = (kq & 1) * 4;
    float bi1[4], bi0[4];
    #pragma unroll
    for (int r = 0; r < 4; ++r) { bi1[r] = b1[ch + r]; bi0[r] = b0[ch + r]; }
    const bool lo = (kq < 2);
    const size_t obase = (size_t)(b * 625 + d01) * 625;
    #pragma unroll
    for (int g = 0; g < 10; ++g) {
        int n = (w * 10 + g) * 16 + col;
        float r0[4], r1[4];
        #pragma unroll
        for (int r = 0; r < 4; ++r) {
            r0[r] = fmaxf(acc0[g][r] + bi1[r], 0.f);
            r1[r] = fmaxf(acc1[g][r] + bi0[r], 0.f);
        }
        us4 u0, u1;
        #pragma unroll
        for (int r = 0; r < 4; ++r) {
            float p0 = __shfl_xor(r0[r], 32, 64);
            float p1 = __shfl_xor(r1[r], 32, 64);
            u0[r] = f2bf(r0[r] + p0);
            u1[r] = f2bf(r1[r] + p1);
        }
        if (lo && n < 625) {
            *(us4*)&hbf[(obase + n) * 16 + 8 + ch] = u0;
            *(us4*)&hbf[(obase + n) * 16 + ch]     = u1;
        }
    }
}

// ---------------- conv16x16 fused pair (unchanged) -------------------------
template <int NTILE, int ADD>
__global__ __launch_bounds__(256) void conv_mfma(
    const unsigned short* __restrict__ in, const unsigned short* __restrict__ wq,
    const float* __restrict__ bias,
    unsigned short* __restrict__ gA, unsigned short* __restrict__ gB,
    float* __restrict__ outp)
{
    __shared__ __align__(16) unsigned short pl[841 * 24];
    const int blk = blockIdx.x;
    const int b = blk / PLANE;
    const int d01 = blk - b * PLANE;
    const int d0 = d01 / S, d1 = d01 - d0 * S;
    const int tid = threadIdx.x;
    const int l = tid & 63, w = tid >> 6;
    const int tp = l >> 5;
    const int kq = (l >> 4) & 3;
    const int h8 = (kq & 1) * 8;
    const int col = l & 15;

    int rb24[10];
    #pragma unroll
    for (int g = 0; g < 10; ++g) {
        int n = (w * 10 + g) * 16 + col;
        if (n > 624) n = 624;
        int d2 = n / 25, d3 = n - d2 * 25;
        rb24[g] = (d2 * 29 + d3) * 24;
    }

    f32x4 acc[10][NTILE];
    #pragma unroll
    for (int g = 0; g < 10; ++g)
        #pragma unroll
        for (int t = 0; t < NTILE; ++t)
            acc[g][t] = (f32x4){0.f, 0.f, 0.f, 0.f};

    #pragma unroll 1
    for (int kd01 = 0; kd01 < 25; ++kd01) {
        const int kd0 = kd01 / 5, kd1 = kd01 - kd0 * 5;
        const int e0 = d0 + kd0 - 2, e1 = d1 + kd1 - 2;
        if (e0 < 0 || e0 >= S || e1 < 0 || e1 >= S) continue;

        __syncthreads();
        {
            const unsigned short* srcp = in + (size_t)(b * 625 + e0 * 25 + e1) * 625 * 16;
            for (int cid = tid; cid < 1682; cid += 256) {
                int r = cid / 58, w8 = cid - r * 58;
                int c = w8 >> 1, hh = w8 & 1;
                u32x4 v = {0u, 0u, 0u, 0u};
                if (r >= 2 && r <= 26 && c >= 2 && c <= 26)
                    v = *(const u32x4*)(srcp + (((r - 2) * 25) + (c - 2)) * 16 + hh * 8);
                *(u32x4*)&pl[(r * 29 + c) * 24 + hh * 8] = v;
            }
        }
        __syncthreads();

        #pragma unroll 1
        for (int pr = 0; pr < 13; ++pr) {
            short8 a0, a1;
            const unsigned short* wp = wq + (size_t)kd01 * 13312 + pr * 1024;
            a0 = *(const short8*)(wp + col * 32 + kq * 8);
            a1 = *(const short8*)(wp + 512 + col * 32 + kq * 8);
            int t = 2 * pr + tp;
            if (t > 24) t = 24;
            int t5 = t / 5;
            int aofs = (t5 * 29 + (t - t5 * 5)) * 24 + h8;
            #pragma unroll
            for (int g = 0; g < 10; ++g) {
                short8 bfrag = *(const short8*)&pl[rb24[g] + aofs];
                acc[g][0] = __builtin_amdgcn_mfma_f32_16x16x32_bf16(a0, bfrag, acc[g][0], 0, 0, 0);
                acc[g][1] = __builtin_amdgcn_mfma_f32_16x16x32_bf16(a1, bfrag, acc[g][1], 0, 0, 0);
            }
        }
    }

    const int cob = kq * 4;
    float bi[4];
    #pragma unroll
    for (int r = 0; r < 4; ++r) bi[r] = bias[cob + r];
    #pragma unroll
    for (int g = 0; g < 10; ++g) {
        int n = (w * 10 + g) * 16 + col;
        if (n < 625) {
            size_t ob = ((size_t)(b * 625 + d01) * 625 + n) * 16 + cob;
            us4 ua, ub;
            #pragma unroll
            for (int r = 0; r < 4; ++r) {
                ua[r] = f2bf(fmaxf(acc[g][0][r] + bi[r], 0.f));
                ub[r] = f2bf(fmaxf(acc[g][1][r] + bi[r], 0.f));
            }
            *(us4*)&gA[ob] = ua;
            *(us4*)&gB[ob] = ub;
        }
    }
}

// ---------------- convc_v2: patch-tiled fused 16->1 pair -------------------
// Block = (b, 2x2 patch of (d0,d1)). LDS [pt 29x29][36]: {gA 16, gB 16, pad 4}
// (72B rows -> conflict-free). 36 slabs/patch. MFMA rows = 4 outputs x 2
// paths; one B-frag read serves all. Epilogue: relu(A+b)+relu(B+b) -> f32.
__global__ __launch_bounds__(512) void convc_v2(
    const unsigned short* __restrict__ gA, const unsigned short* __restrict__ gB,
    const unsigned short* __restrict__ wp2, const float* __restrict__ b2b,
    float* __restrict__ outp)
{
    __shared__ __align__(16) unsigned short pl[841 * 36];
    const int blk = blockIdx.x;
    const int b = blk / 169;
    const int rem = blk - b * 169;
    const int D0 = (rem / 13) * 2, D1 = (rem % 13) * 2;
    const int tid = threadIdx.x;
    const int l = tid & 63, wv = tid >> 6;
    const int col = l & 15, kq = l >> 4;

    int rb[5];
    #pragma unroll
    for (int g = 0; g < 5; ++g) {
        int n = (wv * 5 + g) * 16 + col; if (n > 624) n = 624;
        int d2 = n / 25;
        rb[g] = (d2 * 29 + (n - d2 * 25)) * 36;
    }

    f32x4 acc[5];
    #pragma unroll
    for (int g = 0; g < 5; ++g) acc[g] = (f32x4){0.f, 0.f, 0.f, 0.f};

    #pragma unroll 1
    for (int uv = 0; uv < 36; ++uv) {
        const int u = uv / 6, v6 = uv - u * 6;
        const int e0 = D0 - 2 + u, e1 = D1 - 2 + v6;
        if (e0 < 0 || e0 >= S || e1 < 0 || e1 >= S) continue;  // block-uniform

        __syncthreads();
        {
            const size_t sb = ((size_t)(b * 625 + e0 * 25 + e1)) * 625 * 16;
            for (int cid = tid; cid < 3364; cid += 512) {
                int p = cid >> 2, q = cid & 3;   // q<2: gA halves, q>=2: gB
                int r = p / 29, c = p - r * 29;
                u32x4 z = {0u, 0u, 0u, 0u};
                if (r >= 2 && r <= 26 && c >= 2 && c <= 26) {
                    const unsigned short* src = (q < 2 ? gA : gB) + sb;
                    z = *(const u32x4*)(src + ((r - 2) * 25 + (c - 2)) * 16 + (q & 1) * 8);
                }
                *(u32x4*)&pl[p * 36 + (q >> 1) * 16 + (q & 1) * 8] = z;
            }
        }
        __syncthreads();

        const unsigned short* wbase = wp2 + uv * 25 * 256;
        #pragma unroll 1
        for (int t = 0; t < 25; ++t) {
            const int t5 = t / 5;
            const int toff = (t5 * 29 + (t - t5 * 5)) * 36;
            short8 a = {0, 0, 0, 0, 0, 0, 0, 0};
            if (col < 8)
                a = *(const short8*)(wbase + (t * 8 + col) * 32 + kq * 8);
            #pragma unroll
            for (int g = 0; g < 5; ++g) {
                short8 bf = *(const short8*)&pl[rb[g] + toff + kq * 8];
                acc[g] = __builtin_amdgcn_mfma_f32_16x16x32_bf16(a, bf, acc[g], 0, 0, 0);
            }
        }
    }

    // C row = kq*4+reg; output o = kq*2+oo uses regs 2*oo, 2*oo+1
    if (kq < 2) {
        const float bv = b2b[0];
        #pragma unroll
        for (int g = 0; g < 5; ++g) {
            int n = (wv * 5 + g) * 16 + col;
            if (n < 625) {
                #pragma unroll
                for (int oo = 0; oo < 2; ++oo) {
                    int o = kq * 2 + oo;
                    int d0 = D0 + (o >> 1), d1 = D1 + (o & 1);
                    if (d0 < S && d1 < S) {
                        float vA = acc[g][oo * 2], vB = acc[g][oo * 2 + 1];
                        outp[((size_t)b * 625 + d0 * 25 + d1) * 625 + n] =
                            fmaxf(vA + bv, 0.f) + fmaxf(vB + bv, 0.f);
                    }
                }
            }
        }
    }
}

extern "C" void kernel_launch(void* const* d_in, const int* in_sizes, int n_in,
                              void* d_out, int out_size, void* d_ws, size_t ws_size,
                              hipStream_t stream) {
    const float* x   = (const float*)d_in[0];
    const float* w0  = (const float*)d_in[1];
    const float* b0  = (const float*)d_in[2];
    const float* w1  = (const float*)d_in[3];
    const float* b1  = (const float*)d_in[4];
    const float* w2a = (const float*)d_in[5];
    const float* b2a = (const float*)d_in[6];
    const float* w2b = (const float*)d_in[7];
    const float* b2b = (const float*)d_in[8];
    float* out = (float*)d_out;

    // ws layout (ushort units): hbf | gA | gB | wbig | wl1 | wp2
    const size_t CL = (size_t)2 * 625 * 625 * 16;
    unsigned short* hbf  = (unsigned short*)d_ws;
    unsigned short* gA   = hbf + CL;
    unsigned short* gB   = gA + CL;
    unsigned short* wbig = gB + CL;                  // 332800
    unsigned short* wl1  = wbig + 332800;            // 25600
    unsigned short* wp2  = wl1 + 25600;              // 230400
    if (ws_size < (3 * CL + 332800 + 25600 + 230400) * sizeof(unsigned short)) return;

    const int nblk = 2 * PLANE;  // 1250

    prep_weights<<<2300, 256, 0, stream>>>(w2a, w2b, w0, w1, wbig, wl1, wp2);
    layer1_mfma<<<nblk, 256, 0, stream>>>(x, wl1, b0, b1, hbf);
    conv_mfma<2, 0><<<nblk, 256, 0, stream>>>(hbf, wbig, b2a, gA, gB, nullptr);
    convc_v2<<<338, 512, 0, stream>>>(gA, gB, wp2, b2b, out);
}

// Round 6
// 998.610 us; speedup vs baseline: 20.5302x; 1.1199x over previous
//
#include <hip/hip_runtime.h>

#define S 25
#define PLANE 625
#define VOL 390625
#define CLn 12500000  // ushorts per channels-last activation buffer

typedef __attribute__((ext_vector_type(8))) short short8;
typedef __attribute__((ext_vector_type(4))) float f32x4;
typedef __attribute__((ext_vector_type(4))) unsigned short us4;
typedef __attribute__((ext_vector_type(4))) unsigned int u32x4;

__device__ __forceinline__ unsigned short f2bf(float f) {
    unsigned int u = __float_as_uint(f);
    u += 0x7fffu + ((u >> 16) & 1u);
    return (unsigned short)(u >> 16);
}

// bijective XCD-chunk swizzle (m204): contiguous output ids share an XCD
__device__ __forceinline__ int xcd_swz(int orig, int nwg) {
    int q = nwg >> 3, r = nwg & 7;
    int x = orig & 7, lid = orig >> 3;
    return (x < r ? x * (q + 1) : r * (q + 1) + (x - r) * q) + lid;
}

__device__ __forceinline__ int nxt_kd(int kd, int d0, int d1) {
    #pragma unroll 1
    for (++kd; kd < 25; ++kd) {
        int kd0 = kd / 5, kd1 = kd - kd0 * 5;
        int e0 = d0 + kd0 - 2, e1 = d1 + kd1 - 2;
        if (e0 >= 0 && e0 < S && e1 >= 0 && e1 < S) return kd;
    }
    return 25;
}

__device__ __forceinline__ int nxt_uv(int uv, int D0, int D1) {
    #pragma unroll 1
    for (++uv; uv < 36; ++uv) {
        int u = uv / 6, v6 = uv - u * 6;
        int e0 = D0 - 2 + u, e1 = D1 - 2 + v6;
        if (e0 >= 0 && e0 < S && e1 >= 0 && e1 < S) return uv;
    }
    return 36;
}

// ---------------- weight prep (unchanged from round 5) ---------------------
__global__ __launch_bounds__(256) void prep_weights(
    const float* __restrict__ w2a, const float* __restrict__ w2b,
    const float* __restrict__ w0, const float* __restrict__ w1,
    unsigned short* __restrict__ wbig, unsigned short* __restrict__ wl1,
    unsigned short* __restrict__ wp2)
{
    int idx = blockIdx.x * 256 + threadIdx.x;
    if (idx < 332800) {
        int k = idx & 31;
        int co = (idx >> 5) & 15;
        int tile = (idx >> 9) & 1;
        int rem = idx >> 10;            // kd01*13 + pair
        int pr = rem % 13, kd01 = rem / 13;
        int t = 2 * pr + (k >> 4), ci = k & 15;
        float v = 0.f;
        if (t <= 24)
            v = (tile == 0) ? w2a[(co * 16 + ci) * 625 + kd01 * 25 + t]
                            : w2a[(co * 16 + ci) * 625 + t * 25 + kd01];
        wbig[idx] = f2bf(v);
    } else if (idx < 332800 + 25600) {
        int j = idx - 332800;
        int k = j & 31;
        int row = (j >> 5) & 15;
        int tile = (j >> 9) & 1;
        int kd01 = j >> 10;
        int kd0 = kd01 / 5, kd1 = kd01 - kd0 * 5;
        float v = 0.f;
        if (k < 25) {
            int t = k, kd2 = t / 5, kd3 = t - kd2 * 5;
            if (tile == 0) {
                v = (row < 8) ? w1[row * 625 + kd0 * 125 + kd1 * 25 + t]
                              : w1[(row - 8) * 625 + t * 25 + kd01];
            } else {
                if (row < 8) {
                    if (kd0 >= 1 && kd0 <= 3 && kd1 >= 1 && kd1 <= 3)
                        v = w0[((row * 3 + (kd0 - 1)) * 3 + (kd1 - 1)) * 25 + t];
                } else {
                    if (kd2 >= 1 && kd2 <= 3 && kd3 >= 1 && kd3 <= 3)
                        v = w0[(row - 8) * 225 + ((kd2 - 1) * 3 + (kd3 - 1)) * 25 + kd01];
                }
            }
        }
        wl1[j] = f2bf(v);
    } else if (idx < 332800 + 25600 + 230400) {
        int j = idx - 358400;
        int k = j & 31;
        int row = (j >> 5) & 7;
        int rem = j >> 8;               // uv*25 + t
        int t = rem % 25, uv = rem / 25;
        int u = uv / 6, v6 = uv - u * 6;
        int path = row & 1, o = row >> 1;
        int py = o >> 1, px = o & 1;
        int kd0 = u - py, kd1 = v6 - px;
        float v = 0.f;
        if (kd0 >= 0 && kd0 < 5 && kd1 >= 0 && kd1 < 5) {
            int ci = k & 15;
            if (path == 0 && k < 16)
                v = w2b[ci * 625 + (kd0 * 5 + kd1) * 25 + t];
            else if (path == 1 && k >= 16)
                v = w2b[ci * 625 + t * 25 + kd0 * 5 + kd1];
        }
        wp2[j] = f2bf(v);
    }
}

// ---------------- layer 1, MFMA over taps (unchanged) ----------------------
__global__ __launch_bounds__(256) void layer1_mfma(
    const float* __restrict__ x, const unsigned short* __restrict__ wl1,
    const float* __restrict__ b0, const float* __restrict__ b1,
    unsigned short* __restrict__ hbf)
{
    __shared__ __align__(16) unsigned short pl[29 * 32];
    const int blk = blockIdx.x;
    const int b = blk / PLANE;
    const int d01 = blk - b * PLANE;
    const int d0 = d01 / S, d1 = d01 - d0 * S;
    const int tid = threadIdx.x;
    const int l = tid & 63, w = tid >> 6;
    const int col = l & 15, kq = l >> 4;

    int off[8];
    #pragma unroll
    for (int j = 0; j < 8; ++j) {
        int t = kq * 8 + j; if (t > 24) t = 24;
        int t5 = t / 5;
        off[j] = t5 * 32 + (t - t5 * 5);
    }
    int rb[10];
    #pragma unroll
    for (int g = 0; g < 10; ++g) {
        int n = (w * 10 + g) * 16 + col; if (n > 624) n = 624;
        int d2 = n / 25;
        rb[g] = d2 * 32 + (n - d2 * 25);
    }

    f32x4 acc0[10], acc1[10];
    #pragma unroll
    for (int g = 0; g < 10; ++g) {
        acc0[g] = (f32x4){0.f, 0.f, 0.f, 0.f};
        acc1[g] = (f32x4){0.f, 0.f, 0.f, 0.f};
    }

    const float* xb = x + (size_t)b * VOL;

    #pragma unroll 1
    for (int kd01 = 0; kd01 < 25; ++kd01) {
        const int kd0 = kd01 / 5, kd1 = kd01 - kd0 * 5;
        const int e0 = d0 + kd0 - 2, e1 = d1 + kd1 - 2;
        if (e0 < 0 || e0 >= S || e1 < 0 || e1 >= S) continue;
        __syncthreads();
        {
            const float* sp = xb + (e0 * 25 + e1) * 625;
            for (int i = tid; i < 841; i += 256) {
                int r = i / 29, c = i - r * 29;
                float v = 0.f;
                if (r >= 2 && r <= 26 && c >= 2 && c <= 26)
                    v = sp[(r - 2) * 25 + (c - 2)];
                pl[r * 32 + c] = f2bf(v);
            }
        }
        __syncthreads();
        const unsigned short* wp = wl1 + kd01 * 1024;
        short8 a0 = *(const short8*)(wp + col * 32 + kq * 8);
        short8 a1 = *(const short8*)(wp + 512 + col * 32 + kq * 8);
        #pragma unroll
        for (int g = 0; g < 10; ++g) {
            short8 bf;
            #pragma unroll
            for (int j = 0; j < 8; ++j)
                bf[j] = (short)pl[rb[g] + off[j]];
            acc0[g] = __builtin_amdgcn_mfma_f32_16x16x32_bf16(a0, bf, acc0[g], 0, 0, 0);
            acc1[g] = __builtin_amdgcn_mfma_f32_16x16x32_bf16(a1, bf, acc1[g], 0, 0, 0);
        }
    }

    const int ch = (kq & 1) * 4;
    float bi1[4], bi0[4];
    #pragma unroll
    for (int r = 0; r < 4; ++r) { bi1[r] = b1[ch + r]; bi0[r] = b0[ch + r]; }
    const bool lo = (kq < 2);
    const size_t obase = (size_t)(b * 625 + d01) * 625;
    #pragma unroll
    for (int g = 0; g < 10; ++g) {
        int n = (w * 10 + g) * 16 + col;
        float r0[4], r1[4];
        #pragma unroll
        for (int r = 0; r < 4; ++r) {
            r0[r] = fmaxf(acc0[g][r] + bi1[r], 0.f);
            r1[r] = fmaxf(acc1[g][r] + bi0[r], 0.f);
        }
        us4 u0, u1;
        #pragma unroll
        for (int r = 0; r < 4; ++r) {
            float p0 = __shfl_xor(r0[r], 32, 64);
            float p1 = __shfl_xor(r1[r], 32, 64);
            u0[r] = f2bf(r0[r] + p0);
            u1[r] = f2bf(r1[r] + p1);
        }
        if (lo && n < 625) {
            *(us4*)&hbf[(obase + n) * 16 + 8 + ch] = u0;
            *(us4*)&hbf[(obase + n) * 16 + ch]     = u1;
        }
    }
}

// ---------------- conv16x16 fused pair, T14 pipelined ----------------------
// Per slab: sync -> ds_write(prefetched regs) -> sync -> issue next-slab
// loads -> compute (13 pr x 10 g x 2 MFMA). Loads fly under the MFMA phase.
__global__ __launch_bounds__(256, 3) void conv_mfma(
    const unsigned short* __restrict__ in, const unsigned short* __restrict__ wq,
    const float* __restrict__ bias,
    unsigned short* __restrict__ gA, unsigned short* __restrict__ gB)
{
    __shared__ __align__(16) unsigned short pl[841 * 24];
    const int blk = xcd_swz(blockIdx.x, 1250);
    const int b = blk / PLANE;
    const int d01 = blk - b * PLANE;
    const int d0 = d01 / S, d1 = d01 - d0 * S;
    const int tid = threadIdx.x;
    const int l = tid & 63, w = tid >> 6;
    const int tp = l >> 5;
    const int kq = (l >> 4) & 3;
    const int h8 = (kq & 1) * 8;
    const int col = l & 15;

    // slab-independent staging offsets
    int ofsG[7], ofsL[7]; bool ok[7];
    #pragma unroll
    for (int j = 0; j < 7; ++j) {
        int cid = tid + j * 256;
        int r = cid / 58, w8 = cid - r * 58;
        int c = w8 >> 1, hh = w8 & 1;
        ok[j] = (cid < 1682) && (r >= 2 && r <= 26 && c >= 2 && c <= 26);
        ofsG[j] = ((r - 2) * 25 + (c - 2)) * 16 + hh * 8;
        ofsL[j] = (r * 29 + c) * 24 + hh * 8;
    }

    int rb24[10];
    #pragma unroll
    for (int g = 0; g < 10; ++g) {
        int n = (w * 10 + g) * 16 + col;
        if (n > 624) n = 624;
        int d2 = n / 25, d3 = n - d2 * 25;
        rb24[g] = (d2 * 29 + d3) * 24;
    }

    f32x4 acc[10][2];
    #pragma unroll
    for (int g = 0; g < 10; ++g) {
        acc[g][0] = (f32x4){0.f, 0.f, 0.f, 0.f};
        acc[g][1] = (f32x4){0.f, 0.f, 0.f, 0.f};
    }

    const unsigned short* inb = in + (size_t)b * 625 * 10000;

    u32x4 stg[7];
    int kd_cur = nxt_kd(-1, d0, d1);
    {
        int kd0 = kd_cur / 5, kd1 = kd_cur - kd0 * 5;
        const unsigned short* sb = inb + (size_t)((d0 + kd0 - 2) * 25 + (d1 + kd1 - 2)) * 10000;
        #pragma unroll
        for (int j = 0; j < 7; ++j) {
            u32x4 z = {0u, 0u, 0u, 0u};
            if (ok[j]) z = *(const u32x4*)(sb + ofsG[j]);
            stg[j] = z;
        }
    }

    #pragma unroll 1
    while (kd_cur < 25) {
        const int kd01 = kd_cur;
        const int kd_nxt = nxt_kd(kd_cur, d0, d1);
        __syncthreads();
        #pragma unroll
        for (int j = 0; j < 7; ++j)
            if (j < 6 || tid < 146) *(u32x4*)&pl[ofsL[j]] = stg[j];
        __syncthreads();
        if (kd_nxt < 25) {
            int kd0 = kd_nxt / 5, kd1 = kd_nxt - kd0 * 5;
            const unsigned short* sb = inb + (size_t)((d0 + kd0 - 2) * 25 + (d1 + kd1 - 2)) * 10000;
            #pragma unroll
            for (int j = 0; j < 7; ++j) {
                u32x4 z = {0u, 0u, 0u, 0u};
                if (ok[j]) z = *(const u32x4*)(sb + ofsG[j]);
                stg[j] = z;
            }
        }

        #pragma unroll 1
        for (int pr = 0; pr < 13; ++pr) {
            const unsigned short* wp = wq + (size_t)kd01 * 13312 + pr * 1024;
            short8 a0 = *(const short8*)(wp + col * 32 + kq * 8);
            short8 a1 = *(const short8*)(wp + 512 + col * 32 + kq * 8);
            int t = 2 * pr + tp;
            if (t > 24) t = 24;
            int t5 = t / 5;
            int aofs = (t5 * 29 + (t - t5 * 5)) * 24 + h8;
            #pragma unroll
            for (int g = 0; g < 10; ++g) {
                short8 bfrag = *(const short8*)&pl[rb24[g] + aofs];
                acc[g][0] = __builtin_amdgcn_mfma_f32_16x16x32_bf16(a0, bfrag, acc[g][0], 0, 0, 0);
                acc[g][1] = __builtin_amdgcn_mfma_f32_16x16x32_bf16(a1, bfrag, acc[g][1], 0, 0, 0);
            }
        }
        kd_cur = kd_nxt;
    }

    const int cob = kq * 4;
    float bi[4];
    #pragma unroll
    for (int r = 0; r < 4; ++r) bi[r] = bias[cob + r];
    #pragma unroll
    for (int g = 0; g < 10; ++g) {
        int n = (w * 10 + g) * 16 + col;
        if (n < 625) {
            size_t ob = ((size_t)(b * 625 + d01) * 625 + n) * 16 + cob;
            us4 ua, ub;
            #pragma unroll
            for (int r = 0; r < 4; ++r) {
                ua[r] = f2bf(fmaxf(acc[g][0][r] + bi[r], 0.f));
                ub[r] = f2bf(fmaxf(acc[g][1][r] + bi[r], 0.f));
            }
            *(us4*)&gA[ob] = ua;
            *(us4*)&gB[ob] = ub;
        }
    }
}

// ---------------- convc: patch-tiled fused 16->1 pair, T14 pipelined -------
__global__ __launch_bounds__(512, 4) void convc_v2(
    const unsigned short* __restrict__ gA,   // gB = gA + CLn
    const unsigned short* __restrict__ wp2, const float* __restrict__ b2b,
    float* __restrict__ outp)
{
    __shared__ __align__(16) unsigned short pl[841 * 36];
    const int blk = xcd_swz(blockIdx.x, 338);
    const int b = blk / 169;
    const int rem = blk - b * 169;
    const int D0 = (rem / 13) * 2, D1 = (rem % 13) * 2;
    const int tid = threadIdx.x;
    const int l = tid & 63, wv = tid >> 6;
    const int col = l & 15, kq = l >> 4;

    int ofsG[7], ofsL[7]; bool ok[7];
    #pragma unroll
    for (int j = 0; j < 7; ++j) {
        int cid = tid + j * 512;
        int p = cid >> 2, q = cid & 3;   // q<2: gA halves, q>=2: gB halves
        int r = p / 29, c = p - r * 29;
        ok[j] = (cid < 3364) && (r >= 2 && r <= 26 && c >= 2 && c <= 26);
        ofsG[j] = (q >> 1) * CLn + ((r - 2) * 25 + (c - 2)) * 16 + (q & 1) * 8;
        ofsL[j] = p * 36 + (q >> 1) * 16 + (q & 1) * 8;
    }

    int rb[5];
    #pragma unroll
    for (int g = 0; g < 5; ++g) {
        int n = (wv * 5 + g) * 16 + col; if (n > 624) n = 624;
        int d2 = n / 25;
        rb[g] = (d2 * 29 + (n - d2 * 25)) * 36;
    }

    f32x4 acc[5];
    #pragma unroll
    for (int g = 0; g < 5; ++g) acc[g] = (f32x4){0.f, 0.f, 0.f, 0.f};

    const unsigned short* gAb = gA + (size_t)b * 625 * 10000;

    u32x4 stg[7];
    int uv_cur = nxt_uv(-1, D0, D1);
    {
        int u = uv_cur / 6, v6 = uv_cur - u * 6;
        const unsigned short* sb = gAb + (size_t)((D0 - 2 + u) * 25 + (D1 - 2 + v6)) * 10000;
        #pragma unroll
        for (int j = 0; j < 7; ++j) {
            u32x4 z = {0u, 0u, 0u, 0u};
            if (ok[j]) z = *(const u32x4*)(sb + ofsG[j]);
            stg[j] = z;
        }
    }

    #pragma unroll 1
    while (uv_cur < 36) {
        const int uvc = uv_cur;
        const int uv_nxt = nxt_uv(uv_cur, D0, D1);
        __syncthreads();
        #pragma unroll
        for (int j = 0; j < 7; ++j)
            if (j < 6 || tid < 292) *(u32x4*)&pl[ofsL[j]] = stg[j];
        __syncthreads();
        if (uv_nxt < 36) {
            int u = uv_nxt / 6, v6 = uv_nxt - u * 6;
            const unsigned short* sb = gAb + (size_t)((D0 - 2 + u) * 25 + (D1 - 2 + v6)) * 10000;
            #pragma unroll
            for (int j = 0; j < 7; ++j) {
                u32x4 z = {0u, 0u, 0u, 0u};
                if (ok[j]) z = *(const u32x4*)(sb + ofsG[j]);
                stg[j] = z;
            }
        }

        const unsigned short* wbase = wp2 + uvc * 25 * 256;
        #pragma unroll 1
        for (int t = 0; t < 25; ++t) {
            const int t5 = t / 5;
            const int toff = (t5 * 29 + (t - t5 * 5)) * 36;
            short8 a = {0, 0, 0, 0, 0, 0, 0, 0};
            if (col < 8)
                a = *(const short8*)(wbase + (t * 8 + col) * 32 + kq * 8);
            #pragma unroll
            for (int g = 0; g < 5; ++g) {
                short8 bf = *(const short8*)&pl[rb[g] + toff + kq * 8];
                acc[g] = __builtin_amdgcn_mfma_f32_16x16x32_bf16(a, bf, acc[g], 0, 0, 0);
            }
        }
        uv_cur = uv_nxt;
    }

    // C row = kq*4+reg; output o = kq*2+oo uses regs 2*oo, 2*oo+1
    if (kq < 2) {
        const float bv = b2b[0];
        #pragma unroll
        for (int g = 0; g < 5; ++g) {
            int n = (wv * 5 + g) * 16 + col;
            if (n < 625) {
                #pragma unroll
                for (int oo = 0; oo < 2; ++oo) {
                    int o = kq * 2 + oo;
                    int d0 = D0 + (o >> 1), d1 = D1 + (o & 1);
                    if (d0 < S && d1 < S) {
                        float vA = acc[g][oo * 2], vB = acc[g][oo * 2 + 1];
                        outp[((size_t)b * 625 + d0 * 25 + d1) * 625 + n] =
                            fmaxf(vA + bv, 0.f) + fmaxf(vB + bv, 0.f);
                    }
                }
            }
        }
    }
}

extern "C" void kernel_launch(void* const* d_in, const int* in_sizes, int n_in,
                              void* d_out, int out_size, void* d_ws, size_t ws_size,
                              hipStream_t stream) {
    const float* x   = (const float*)d_in[0];
    const float* w0  = (const float*)d_in[1];
    const float* b0  = (const float*)d_in[2];
    const float* w1  = (const float*)d_in[3];
    const float* b1  = (const float*)d_in[4];
    const float* w2a = (const float*)d_in[5];
    const float* b2a = (const float*)d_in[6];
    const float* w2b = (const float*)d_in[7];
    const float* b2b = (const float*)d_in[8];
    float* out = (float*)d_out;

    // ws layout (ushort units): hbf | gA | gB | wbig | wl1 | wp2
    unsigned short* hbf  = (unsigned short*)d_ws;
    unsigned short* gA   = hbf + CLn;
    unsigned short* gB   = gA + CLn;                 // gB must stay gA+CLn
    unsigned short* wbig = gB + CLn;                 // 332800
    unsigned short* wl1  = wbig + 332800;            // 25600
    unsigned short* wp2  = wl1 + 25600;              // 230400
    if (ws_size < ((size_t)3 * CLn + 332800 + 25600 + 230400) * sizeof(unsigned short)) return;

    const int nblk = 2 * PLANE;  // 1250

    prep_weights<<<2300, 256, 0, stream>>>(w2a, w2b, w0, w1, wbig, wl1, wp2);
    layer1_mfma<<<nblk, 256, 0, stream>>>(x, wl1, b0, b1, hbf);
    conv_mfma<<<nblk, 256, 0, stream>>>(hbf, wbig, b2a, gA, gB);
    convc_v2<<<338, 512, 0, stream>>>(gA, wp2, b2b, out);
}